// Round 1
// baseline (477.104 us; speedup 1.0000x reference)
//
#include <hip/hip_runtime.h>

typedef unsigned short u16;
typedef __bf16 bf16x8 __attribute__((ext_vector_type(8)));
typedef u16 u16x8 __attribute__((ext_vector_type(8)));
typedef float f32x4 __attribute__((ext_vector_type(4)));

__device__ __forceinline__ u16 f2bf(float f) {
    unsigned u = __float_as_uint(f);
    return (u16)((u + 0x7fffu + ((u >> 16) & 1u)) >> 16);
}

// ---------------- fp32 -> bf16 convert ----------------
__global__ void cvt_bf16(const float* __restrict__ src, u16* __restrict__ dst, int n4) {
    int i = blockIdx.x * 256 + threadIdx.x;
    if (i >= n4) return;
    float4 v = *(const float4*)(src + (size_t)i * 4);
    unsigned lo = (unsigned)f2bf(v.x) | ((unsigned)f2bf(v.y) << 16);
    unsigned hi = (unsigned)f2bf(v.z) | ((unsigned)f2bf(v.w) << 16);
    uint2 o; o.x = lo; o.y = hi;
    *(uint2*)(dst + (size_t)i * 4) = o;
}

// ---------------- bf16 GEMM: C[M][N] = A[M][K] * B[N][K]^T, fp32 out --------
// m97 recipe: 128x128 tile, BK=32, 4 waves, 16x16x32 MFMA, global_load_lds x16
__global__ __launch_bounds__(256)
void gemm_bt(const u16* __restrict__ A, const u16* __restrict__ B,
             float* __restrict__ C, int M, int N, int K) {
    __shared__ u16 As[128 * 32];
    __shared__ u16 Bs[128 * 32];
    const int tid = threadIdx.x;
    const int wave = tid >> 6, lane = tid & 63;
    const int quad = lane >> 4, l16 = lane & 15;
    const size_t bm = (size_t)blockIdx.y * 128;
    const size_t bn = (size_t)blockIdx.x * 128;
    const int wr = (wave >> 1) * 64;
    const int wc = (wave & 1) * 64;

    f32x4 acc[4][4] = {};

    const u16* Ab = A + bm * K;
    const u16* Bb = B + bn * K;
    const int strow = wave * 32 + (lane >> 2);  // staging row (per chunk +16)
    const int stk = (lane & 3) * 8;             // staging k-offset (elems)

    for (int k0 = 0; k0 < K; k0 += 32) {
        __syncthreads();
#pragma unroll
        for (int c = 0; c < 2; ++c) {
            const u16* ga = Ab + (size_t)(strow + c * 16) * K + k0 + stk;
            const u16* gb = Bb + (size_t)(strow + c * 16) * K + k0 + stk;
            __builtin_amdgcn_global_load_lds(
                (__attribute__((address_space(1))) void*)ga,
                (__attribute__((address_space(3))) void*)&As[(wave * 32 + c * 16) * 32],
                16, 0, 0);
            __builtin_amdgcn_global_load_lds(
                (__attribute__((address_space(1))) void*)gb,
                (__attribute__((address_space(3))) void*)&Bs[(wave * 32 + c * 16) * 32],
                16, 0, 0);
        }
        __syncthreads();
        bf16x8 af[4], bfr[4];
#pragma unroll
        for (int mt = 0; mt < 4; ++mt)
            af[mt] = *(const bf16x8*)&As[(wr + mt * 16 + l16) * 32 + quad * 8];
#pragma unroll
        for (int nt = 0; nt < 4; ++nt)
            bfr[nt] = *(const bf16x8*)&Bs[(wc + nt * 16 + l16) * 32 + quad * 8];
#pragma unroll
        for (int mt = 0; mt < 4; ++mt)
#pragma unroll
            for (int nt = 0; nt < 4; ++nt)
                acc[mt][nt] = __builtin_amdgcn_mfma_f32_16x16x32_bf16(
                    af[mt], bfr[nt], acc[mt][nt], 0, 0, 0);
    }
#pragma unroll
    for (int mt = 0; mt < 4; ++mt)
#pragma unroll
        for (int nt = 0; nt < 4; ++nt)
#pragma unroll
            for (int r = 0; r < 4; ++r)
                C[(bm + wr + mt * 16 + quad * 4 + r) * (size_t)N + bn + wc + nt * 16 + l16] =
                    acc[mt][nt][r];
}

// ---------------- RMSNorm + RoPE for q,k (one wave per row*head-task) -------
__global__ __launch_bounds__(256)
void normrope(const float* __restrict__ qkv, const float* __restrict__ qw,
              const float* __restrict__ kw, const float* __restrict__ fcos,
              const float* __restrict__ fsin, u16* __restrict__ qb, u16* __restrict__ kb) {
    int gw = blockIdx.x * 4 + (threadIdx.x >> 6);  // 0 .. 4096*20-1
    int lane = threadIdx.x & 63;
    int row = gw / 20;       // 0..4095 (= b*2048 + s)
    int task = gw - row * 20;
    int s = row & 2047;
    int b = row >> 11;
    const float* src;
    const float* w;
    u16* dst;
    if (task < 16) {
        src = qkv + (size_t)row * 3072 + task * 128;
        w = qw;
        dst = qb + ((size_t)(b * 16 + task) * 2048 + s) * 128;
    } else {
        int kh = task - 16;
        src = qkv + (size_t)row * 3072 + 2048 + kh * 128;
        w = kw;
        dst = kb + ((size_t)(b * 4 + kh) * 2048 + s) * 128;
    }
    float2 x = *(const float2*)(src + lane * 2);
    float ss = x.x * x.x + x.y * x.y;
#pragma unroll
    for (int off = 32; off >= 1; off >>= 1) ss += __shfl_xor(ss, off);
    float r = rsqrtf(ss * (1.0f / 128.0f) + 1.1920928955078125e-07f);
    float y0 = x.x * r * w[lane * 2];
    float y1 = x.y * r * w[lane * 2 + 1];
    float c0 = fcos[(size_t)s * 128 + lane * 2], c1 = fcos[(size_t)s * 128 + lane * 2 + 1];
    float s0 = fsin[(size_t)s * 128 + lane * 2], s1 = fsin[(size_t)s * 128 + lane * 2 + 1];
    dst[lane * 2]     = f2bf(y0 * c0 - y1 * s0);
    dst[lane * 2 + 1] = f2bf(y1 * c1 + y0 * s1);
}

// ---------------- V transpose: qkv fp32 [.,2560+kv*128+d] -> vt bf16 [b,kv,d,s]
__global__ __launch_bounds__(256)
void vtrans(const float* __restrict__ qkv, u16* __restrict__ vt) {
    __shared__ u16 tile[128 * 132];
    int blk = blockIdx.x;
    int kblk = blk & 15, kh = (blk >> 4) & 3, b = blk >> 6;
    int tid = threadIdx.x;
    const float* src = qkv + (size_t)(b * 2048 + kblk * 128) * 3072 + 2560 + kh * 128;
#pragma unroll
    for (int it = 0; it < 16; ++it) {
        int flat4 = tid + it * 256;           // 0..4095, one float4 each
        int row = flat4 >> 5, c4 = flat4 & 31;
        float4 v = *(const float4*)(src + (size_t)row * 3072 + c4 * 4);
        u16* d = &tile[row * 132 + c4 * 4];
        d[0] = f2bf(v.x); d[1] = f2bf(v.y); d[2] = f2bf(v.z); d[3] = f2bf(v.w);
    }
    __syncthreads();
    int dd = tid >> 1, half = tid & 1;
    u16* dst = vt + ((size_t)(b * 4 + kh) * 128 + dd) * 2048 + kblk * 128 + half * 64;
#pragma unroll
    for (int k8 = 0; k8 < 8; ++k8) {
        u16x8 o;
#pragma unroll
        for (int j = 0; j < 8; ++j) o[j] = tile[(half * 64 + k8 * 8 + j) * 132 + dd];
        *(u16x8*)(dst + k8 * 8) = o;
    }
}

// ---------------- flash attention: block=(qt,h,b), 128 q-rows, 64-key tiles --
__global__ __launch_bounds__(256)
void flash_attn(const u16* __restrict__ qb, const u16* __restrict__ kb,
                const u16* __restrict__ vt, u16* __restrict__ ab) {
    __shared__ u16 Klds[64 * 136];      // [key][d] pad 8
    __shared__ u16 Vlds[128 * 72];      // [d][key] pad 8
    __shared__ u16 Plds[4 * 32 * 72];   // per-wave [qrow][key] pad 8

    const int tid = threadIdx.x;
    const int wave = tid >> 6, lane = tid & 63;
    const int quad = lane >> 4, l16 = lane & 15;
    const int qt = blockIdx.x, h = blockIdx.y, b = blockIdx.z;
    const int kh = h >> 2;

    const u16* Qbase = qb + (size_t)(b * 16 + h) * 2048 * 128;
    const u16* Kbase = kb + (size_t)(b * 4 + kh) * 2048 * 128;
    const u16* Vbase = vt + (size_t)(b * 4 + kh) * 128 * 2048;

    // resident Q fragments (A-layout): rows wave*32 + mt*16 + l16
    bf16x8 aq[2][4];
#pragma unroll
    for (int mt = 0; mt < 2; ++mt) {
        int srow = qt * 128 + wave * 32 + mt * 16 + l16;
#pragma unroll
        for (int kc = 0; kc < 4; ++kc)
            aq[mt][kc] = *(const bf16x8*)(Qbase + (size_t)srow * 128 + kc * 32 + quad * 8);
    }

    f32x4 O[2][8] = {};
    float m_run[2][4], l_run[2][4];
#pragma unroll
    for (int mt = 0; mt < 2; ++mt)
#pragma unroll
        for (int r = 0; r < 4; ++r) { m_run[mt][r] = -1e30f; l_run[mt][r] = 0.f; }

    u16* Pw = &Plds[wave * 32 * 72];

    for (int kt = 0; kt < 32; ++kt) {
        const int key0 = kt * 64;
        __syncthreads();
        // stage K tile: 64 keys x 128 d
#pragma unroll
        for (int it = 0; it < 4; ++it) {
            int flat = tid + it * 256;  // 0..1023
            int row = flat >> 4, c16 = flat & 15;
            u16x8 v = *(const u16x8*)(Kbase + (size_t)(key0 + row) * 128 + c16 * 8);
            *(u16x8*)&Klds[row * 136 + c16 * 8] = v;
        }
        // stage V^T tile: 128 d x 64 keys
#pragma unroll
        for (int it = 0; it < 4; ++it) {
            int flat = tid + it * 256;  // 0..1023
            int dr = flat >> 3, c8 = flat & 7;
            u16x8 v = *(const u16x8*)(Vbase + (size_t)dr * 2048 + key0 + c8 * 8);
            *(u16x8*)&Vlds[dr * 72 + c8 * 8] = v;
        }
        __syncthreads();

        // scores = Q K^T * scale
        f32x4 sc[2][4] = {};
#pragma unroll
        for (int nt = 0; nt < 4; ++nt) {
            bf16x8 bk[4];
#pragma unroll
            for (int kc = 0; kc < 4; ++kc)
                bk[kc] = *(const bf16x8*)&Klds[(nt * 16 + l16) * 136 + kc * 32 + quad * 8];
#pragma unroll
            for (int mt = 0; mt < 2; ++mt)
#pragma unroll
                for (int kc = 0; kc < 4; ++kc)
                    sc[mt][nt] = __builtin_amdgcn_mfma_f32_16x16x32_bf16(
                        aq[mt][kc], bk[kc], sc[mt][nt], 0, 0, 0);
        }
#pragma unroll
        for (int mt = 0; mt < 2; ++mt)
#pragma unroll
            for (int nt = 0; nt < 4; ++nt) sc[mt][nt] *= 0.08838834764831845f;

        // online softmax
        float alpha[2][4];
#pragma unroll
        for (int mt = 0; mt < 2; ++mt) {
#pragma unroll
            for (int r = 0; r < 4; ++r) {
                float vm = -1e30f;
#pragma unroll
                for (int nt = 0; nt < 4; ++nt) vm = fmaxf(vm, sc[mt][nt][r]);
                vm = fmaxf(vm, __shfl_xor(vm, 1));
                vm = fmaxf(vm, __shfl_xor(vm, 2));
                vm = fmaxf(vm, __shfl_xor(vm, 4));
                vm = fmaxf(vm, __shfl_xor(vm, 8));
                float mn = fmaxf(m_run[mt][r], vm);
                float al = __expf(m_run[mt][r] - mn);
                m_run[mt][r] = mn;
                alpha[mt][r] = al;
                float rs = 0.f;
#pragma unroll
                for (int nt = 0; nt < 4; ++nt) {
                    float p = __expf(sc[mt][nt][r] - mn);
                    sc[mt][nt][r] = p;
                    rs += p;
                }
                rs += __shfl_xor(rs, 1);
                rs += __shfl_xor(rs, 2);
                rs += __shfl_xor(rs, 4);
                rs += __shfl_xor(rs, 8);
                l_run[mt][r] = l_run[mt][r] * al + rs;
            }
        }
        // P -> LDS (C-layout scatter), rescale O
#pragma unroll
        for (int mt = 0; mt < 2; ++mt)
#pragma unroll
            for (int nt = 0; nt < 4; ++nt)
#pragma unroll
                for (int r = 0; r < 4; ++r)
                    Pw[(mt * 16 + quad * 4 + r) * 72 + nt * 16 + l16] = f2bf(sc[mt][nt][r]);
#pragma unroll
        for (int mt = 0; mt < 2; ++mt)
#pragma unroll
            for (int dt = 0; dt < 8; ++dt) {
                O[mt][dt][0] *= alpha[mt][0];
                O[mt][dt][1] *= alpha[mt][1];
                O[mt][dt][2] *= alpha[mt][2];
                O[mt][dt][3] *= alpha[mt][3];
            }
        __syncthreads();

        // O += P V  (P in A-layout from LDS, V^T rows as B operand)
        bf16x8 ap[2][2];
#pragma unroll
        for (int mt = 0; mt < 2; ++mt)
#pragma unroll
            for (int kc = 0; kc < 2; ++kc)
                ap[mt][kc] = *(const bf16x8*)&Pw[(mt * 16 + l16) * 72 + kc * 32 + quad * 8];
#pragma unroll
        for (int dt = 0; dt < 8; ++dt) {
            bf16x8 bv[2];
#pragma unroll
            for (int kc = 0; kc < 2; ++kc)
                bv[kc] = *(const bf16x8*)&Vlds[(dt * 16 + l16) * 72 + kc * 32 + quad * 8];
#pragma unroll
            for (int mt = 0; mt < 2; ++mt)
#pragma unroll
                for (int kc = 0; kc < 2; ++kc)
                    O[mt][dt] = __builtin_amdgcn_mfma_f32_16x16x32_bf16(
                        ap[mt][kc], bv[kc], O[mt][dt], 0, 0, 0);
        }
    }
    // epilogue: ab[b*2048+s][h*128+d] = O / l   (bf16)
#pragma unroll
    for (int mt = 0; mt < 2; ++mt) {
#pragma unroll
        for (int r = 0; r < 4; ++r) {
            int srow = qt * 128 + wave * 32 + mt * 16 + quad * 4 + r;
            float inv = 1.0f / l_run[mt][r];
            u16* dst = ab + (size_t)(b * 2048 + srow) * 2048 + h * 128;
#pragma unroll
            for (int dt = 0; dt < 8; ++dt)
                dst[dt * 16 + l16] = f2bf(O[mt][dt][r] * inv);
        }
    }
}

// ---------------- host launch ----------------
extern "C" void kernel_launch(void* const* d_in, const int* in_sizes, int n_in,
                              void* d_out, int out_size, void* d_ws, size_t ws_size,
                              hipStream_t stream) {
    const float* x    = (const float*)d_in[0];
    const float* wqkv = (const float*)d_in[1];
    const float* wo   = (const float*)d_in[2];
    const float* qw   = (const float*)d_in[3];
    const float* kw   = (const float*)d_in[4];
    const float* fc   = (const float*)d_in[5];
    const float* fs   = (const float*)d_in[6];
    float* out = (float*)d_out;
    char* ws = (char*)d_ws;

    // ws layout (bytes, all 256-aligned)
    u16*   xb    = (u16*)(ws + 0);           // 4096x2048 bf16   (16 MB)
    u16*   wqkvb = (u16*)(ws + 16777216);    // 3072x2048 bf16   (12 MB)
    u16*   wob   = (u16*)(ws + 29360128);    // 2048x2048 bf16   ( 8 MB)
    float* qkv   = (float*)(ws + 37748736);  // 4096x3072 fp32   (48 MB)
    u16*   qb    = (u16*)(ws + 88080384);    // [2,16,2048,128]  (16 MB)
    u16*   kb    = (u16*)(ws + 104857600);   // [2,4,2048,128]   ( 4 MB)
    u16*   vt    = (u16*)(ws + 109051904);   // [2,4,128,2048]   ( 4 MB)
    u16*   ab    = (u16*)(ws + 113246208);   // 4096x2048 bf16   (16 MB)

    cvt_bf16<<<8192, 256, 0, stream>>>(x, xb, 2097152);
    cvt_bf16<<<6144, 256, 0, stream>>>(wqkv, wqkvb, 1572864);
    cvt_bf16<<<4096, 256, 0, stream>>>(wo, wob, 1048576);
    gemm_bt<<<dim3(24, 32), 256, 0, stream>>>(xb, wqkvb, qkv, 4096, 3072, 2048);
    normrope<<<20480, 256, 0, stream>>>(qkv, qw, kw, fc, fs, qb, kb);
    vtrans<<<128, 256, 0, stream>>>(qkv, vt);
    flash_attn<<<dim3(16, 16, 2), 256, 0, stream>>>(qb, kb, vt, ab);
    gemm_bt<<<dim3(16, 32), 256, 0, stream>>>(ab, wob, out, 4096, 2048, 2048);
}

// Round 2
// 448.137 us; speedup vs baseline: 1.0646x; 1.0646x over previous
//
#include <hip/hip_runtime.h>

typedef unsigned short u16;
typedef __bf16 bf16x8 __attribute__((ext_vector_type(8)));
typedef __bf16 bf16x4 __attribute__((ext_vector_type(4)));
typedef u16 u16x8 __attribute__((ext_vector_type(8)));
typedef float f32x4 __attribute__((ext_vector_type(4)));

__device__ __forceinline__ u16 f2bf(float f) {
    unsigned u = __float_as_uint(f);
    return (u16)((u + 0x7fffu + ((u >> 16) & 1u)) >> 16);
}

// ---------------- fp32 -> bf16 convert ----------------
__global__ void cvt_bf16(const float* __restrict__ src, u16* __restrict__ dst, int n4) {
    int i = blockIdx.x * 256 + threadIdx.x;
    if (i >= n4) return;
    float4 v = *(const float4*)(src + (size_t)i * 4);
    unsigned lo = (unsigned)f2bf(v.x) | ((unsigned)f2bf(v.y) << 16);
    unsigned hi = (unsigned)f2bf(v.z) | ((unsigned)f2bf(v.w) << 16);
    uint2 o; o.x = lo; o.y = hi;
    *(uint2*)(dst + (size_t)i * 4) = o;
}

// ---------------- bf16 GEMM: C[M][N] = A[M][K] * B[N][K]^T, fp32 out --------
__global__ __launch_bounds__(256)
void gemm_bt(const u16* __restrict__ A, const u16* __restrict__ B,
             float* __restrict__ C, int M, int N, int K) {
    __shared__ u16 As[128 * 32];
    __shared__ u16 Bs[128 * 32];
    const int tid = threadIdx.x;
    const int wave = tid >> 6, lane = tid & 63;
    const int quad = lane >> 4, l16 = lane & 15;
    const size_t bm = (size_t)blockIdx.y * 128;
    const size_t bn = (size_t)blockIdx.x * 128;
    const int wr = (wave >> 1) * 64;
    const int wc = (wave & 1) * 64;

    f32x4 acc[4][4] = {};

    const u16* Ab = A + bm * K;
    const u16* Bb = B + bn * K;
    const int strow = wave * 32 + (lane >> 2);
    const int stk = (lane & 3) * 8;

    for (int k0 = 0; k0 < K; k0 += 32) {
        __syncthreads();
#pragma unroll
        for (int c = 0; c < 2; ++c) {
            const u16* ga = Ab + (size_t)(strow + c * 16) * K + k0 + stk;
            const u16* gb = Bb + (size_t)(strow + c * 16) * K + k0 + stk;
            __builtin_amdgcn_global_load_lds(
                (__attribute__((address_space(1))) void*)ga,
                (__attribute__((address_space(3))) void*)&As[(wave * 32 + c * 16) * 32],
                16, 0, 0);
            __builtin_amdgcn_global_load_lds(
                (__attribute__((address_space(1))) void*)gb,
                (__attribute__((address_space(3))) void*)&Bs[(wave * 32 + c * 16) * 32],
                16, 0, 0);
        }
        __syncthreads();
        bf16x8 af[4], bfr[4];
#pragma unroll
        for (int mt = 0; mt < 4; ++mt)
            af[mt] = *(const bf16x8*)&As[(wr + mt * 16 + l16) * 32 + quad * 8];
#pragma unroll
        for (int nt = 0; nt < 4; ++nt)
            bfr[nt] = *(const bf16x8*)&Bs[(wc + nt * 16 + l16) * 32 + quad * 8];
#pragma unroll
        for (int mt = 0; mt < 4; ++mt)
#pragma unroll
            for (int nt = 0; nt < 4; ++nt)
                acc[mt][nt] = __builtin_amdgcn_mfma_f32_16x16x32_bf16(
                    af[mt], bfr[nt], acc[mt][nt], 0, 0, 0);
    }
#pragma unroll
    for (int mt = 0; mt < 4; ++mt)
#pragma unroll
        for (int nt = 0; nt < 4; ++nt)
#pragma unroll
            for (int r = 0; r < 4; ++r)
                C[(bm + wr + mt * 16 + quad * 4 + r) * (size_t)N + bn + wc + nt * 16 + l16] =
                    acc[mt][nt][r];
}

// ---------------- RMSNorm + RoPE for q,k. Q pre-scaled by scale*log2(e) -----
__global__ __launch_bounds__(256)
void normrope(const float* __restrict__ qkv, const float* __restrict__ qw,
              const float* __restrict__ kw, const float* __restrict__ fcos,
              const float* __restrict__ fsin, u16* __restrict__ qb, u16* __restrict__ kb) {
    int gw = blockIdx.x * 4 + (threadIdx.x >> 6);
    int lane = threadIdx.x & 63;
    int row = gw / 20;
    int task = gw - row * 20;
    int s = row & 2047;
    int b = row >> 11;
    const float* src;
    const float* w;
    u16* dst;
    float scl;
    if (task < 16) {
        src = qkv + (size_t)row * 3072 + task * 128;
        w = qw;
        dst = qb + ((size_t)(b * 16 + task) * 2048 + s) * 128;
        scl = 0.08838834764831845f * 1.4426950408889634f;  // scale * log2(e)
    } else {
        int kh = task - 16;
        src = qkv + (size_t)row * 3072 + 2048 + kh * 128;
        w = kw;
        dst = kb + ((size_t)(b * 4 + kh) * 2048 + s) * 128;
        scl = 1.0f;
    }
    float2 x = *(const float2*)(src + lane * 2);
    float ss = x.x * x.x + x.y * x.y;
#pragma unroll
    for (int off = 32; off >= 1; off >>= 1) ss += __shfl_xor(ss, off);
    float r = rsqrtf(ss * (1.0f / 128.0f) + 1.1920928955078125e-07f) * scl;
    float y0 = x.x * r * w[lane * 2];
    float y1 = x.y * r * w[lane * 2 + 1];
    float c0 = fcos[(size_t)s * 128 + lane * 2], c1 = fcos[(size_t)s * 128 + lane * 2 + 1];
    float s0 = fsin[(size_t)s * 128 + lane * 2], s1 = fsin[(size_t)s * 128 + lane * 2 + 1];
    dst[lane * 2]     = f2bf(y0 * c0 - y1 * s0);
    dst[lane * 2 + 1] = f2bf(y1 * c1 + y0 * s1);
}

// ---------------- V transpose: qkv fp32 -> vt bf16 [b,kv,d,s] ----------------
__global__ __launch_bounds__(256)
void vtrans(const float* __restrict__ qkv, u16* __restrict__ vt) {
    __shared__ u16 tile[128 * 132];
    int blk = blockIdx.x;
    int kblk = blk & 15, kh = (blk >> 4) & 3, b = blk >> 6;
    int tid = threadIdx.x;
    const float* src = qkv + (size_t)(b * 2048 + kblk * 128) * 3072 + 2560 + kh * 128;
#pragma unroll
    for (int it = 0; it < 16; ++it) {
        int flat4 = tid + it * 256;
        int row = flat4 >> 5, c4 = flat4 & 31;
        float4 v = *(const float4*)(src + (size_t)row * 3072 + c4 * 4);
        u16* d = &tile[row * 132 + c4 * 4];
        d[0] = f2bf(v.x); d[1] = f2bf(v.y); d[2] = f2bf(v.z); d[3] = f2bf(v.w);
    }
    __syncthreads();
    int dd = tid >> 1, half = tid & 1;
    u16* dst = vt + ((size_t)(b * 4 + kh) * 128 + dd) * 2048 + kblk * 128 + half * 64;
#pragma unroll
    for (int k8 = 0; k8 < 8; ++k8) {
        u16x8 o;
#pragma unroll
        for (int j = 0; j < 8; ++j) o[j] = tile[(half * 64 + k8 * 8 + j) * 132 + dd];
        *(u16x8*)(dst + k8 * 8) = o;
    }
}

// ---------------- flash attention (no-max softmax, S^T trick) ----------------
// block=(qt,h,b): 128 q-rows, 4 waves x 32 rows, 64-key tiles.
__global__ __launch_bounds__(256, 2)
void flash_attn(const u16* __restrict__ qb, const u16* __restrict__ kb,
                const u16* __restrict__ vt, u16* __restrict__ ab) {
    __shared__ u16 Klds[64 * 134];      // [key][d]   stride 67 words (== 3 mod 32)
    __shared__ u16 Vlds[128 * 70];      // [d][key]   stride 35 words (== 3 mod 32)
    __shared__ u16 Plds[4 * 32 * 70];   // per-wave P^... [qrow][key], stride 35 words
    __shared__ float Llds[4 * 32];

    const int tid = threadIdx.x;
    const int wave = tid >> 6, lane = tid & 63;
    const int quad = lane >> 4, l16 = lane & 15;
    const int qt = blockIdx.x, h = blockIdx.y, b = blockIdx.z;
    const int kh = h >> 2;

    const u16* Qbase = qb + (size_t)(b * 16 + h) * 2048 * 128;
    const u16* Kbase = kb + (size_t)(b * 4 + kh) * 2048 * 128;
    const u16* Vbase = vt + (size_t)(b * 4 + kh) * 128 * 2048;

    // resident Q fragments: rows wave*32 + nt*16 + l16 (used as B-operand for S^T)
    bf16x8 aq[2][4];
#pragma unroll
    for (int nt = 0; nt < 2; ++nt) {
        int srow = qt * 128 + wave * 32 + nt * 16 + l16;
#pragma unroll
        for (int kc = 0; kc < 4; ++kc)
            aq[nt][kc] = *(const bf16x8*)(Qbase + (size_t)srow * 128 + kc * 32 + quad * 8);
    }

    f32x4 O[2][8] = {};
    f32x4 lacc[2] = {};   // per-lane partial softmax denominators

    u16* Pw = &Plds[wave * 32 * 70];

    for (int kt = 0; kt < 32; ++kt) {
        const int key0 = kt * 64;
        __syncthreads();
        // stage K tile: 64 keys x 128 d
#pragma unroll
        for (int it = 0; it < 4; ++it) {
            int flat = tid + it * 256;
            int row = flat >> 4, c16 = flat & 15;
            u16x8 v = *(const u16x8*)(Kbase + (size_t)(key0 + row) * 128 + c16 * 8);
            *(u16x8*)&Klds[row * 134 + c16 * 8] = v;
        }
        // stage V^T tile: 128 d x 64 keys
#pragma unroll
        for (int it = 0; it < 4; ++it) {
            int flat = tid + it * 256;
            int dr = flat >> 3, c8 = flat & 7;
            u16x8 v = *(const u16x8*)(Vbase + (size_t)dr * 2048 + key0 + c8 * 8);
            *(u16x8*)&Vlds[dr * 70 + c8 * 8] = v;
        }
        __syncthreads();

        // S^T = K * Q^T  (C-layout: row = key = quad*4+r, col = qrow = l16)
        f32x4 sc[4][2] = {};
#pragma unroll
        for (int mt = 0; mt < 4; ++mt) {
            bf16x8 bk[4];
#pragma unroll
            for (int kc = 0; kc < 4; ++kc)
                bk[kc] = *(const bf16x8*)&Klds[(mt * 16 + l16) * 134 + kc * 32 + quad * 8];
#pragma unroll
            for (int nt = 0; nt < 2; ++nt)
#pragma unroll
                for (int kc = 0; kc < 4; ++kc)
                    sc[mt][nt] = __builtin_amdgcn_mfma_f32_16x16x32_bf16(
                        bk[kc], aq[nt][kc], sc[mt][nt], 0, 0, 0);
        }

        // p = exp2(s) (scale*log2e folded into Q; |s| <= 16.4 so no max needed),
        // accumulate l, pack 4 consecutive keys -> one b64 LDS write.
#pragma unroll
        for (int mt = 0; mt < 4; ++mt)
#pragma unroll
            for (int nt = 0; nt < 2; ++nt) {
                f32x4 p;
#pragma unroll
                for (int r = 0; r < 4; ++r) p[r] = __builtin_amdgcn_exp2f(sc[mt][nt][r]);
                lacc[nt] += p;
                bf16x4 pb;
#pragma unroll
                for (int r = 0; r < 4; ++r) pb[r] = (__bf16)p[r];
                *(bf16x4*)&Pw[(nt * 16 + l16) * 70 + mt * 16 + quad * 4] = pb;
            }

        // O += P V   (intra-wave LDS RAW: compiler inserts lgkmcnt, no barrier)
        bf16x8 ap[2][2];
#pragma unroll
        for (int nt = 0; nt < 2; ++nt)
#pragma unroll
            for (int kc = 0; kc < 2; ++kc)
                ap[nt][kc] = *(const bf16x8*)&Pw[(nt * 16 + l16) * 70 + kc * 32 + quad * 8];
#pragma unroll
        for (int dt = 0; dt < 8; ++dt) {
            bf16x8 bv[2];
#pragma unroll
            for (int kc = 0; kc < 2; ++kc)
                bv[kc] = *(const bf16x8*)&Vlds[(dt * 16 + l16) * 70 + kc * 32 + quad * 8];
#pragma unroll
            for (int nt = 0; nt < 2; ++nt)
#pragma unroll
                for (int kc = 0; kc < 2; ++kc)
                    O[nt][dt] = __builtin_amdgcn_mfma_f32_16x16x32_bf16(
                        ap[nt][kc], bv[kc], O[nt][dt], 0, 0, 0);
        }
    }

    // final l reduction (once per kernel, not per tile)
#pragma unroll
    for (int nt = 0; nt < 2; ++nt) {
        float l = lacc[nt][0] + lacc[nt][1] + lacc[nt][2] + lacc[nt][3];
        l += __shfl_xor(l, 16);
        l += __shfl_xor(l, 32);
        Llds[wave * 32 + nt * 16 + l16] = l;  // all quads write identical value
    }
    __syncthreads();

    // epilogue: ab[b*2048+s][h*128+d] = O / l
#pragma unroll
    for (int nt = 0; nt < 2; ++nt) {
#pragma unroll
        for (int r = 0; r < 4; ++r) {
            int qrow = nt * 16 + quad * 4 + r;
            float inv = __builtin_amdgcn_rcpf(Llds[wave * 32 + qrow]);
            int srow = qt * 128 + wave * 32 + qrow;
            u16* dst = ab + (size_t)(b * 2048 + srow) * 2048 + h * 128;
#pragma unroll
            for (int dt = 0; dt < 8; ++dt)
                dst[dt * 16 + l16] = f2bf(O[nt][dt][r] * inv);
        }
    }
}

// ---------------- host launch ----------------
extern "C" void kernel_launch(void* const* d_in, const int* in_sizes, int n_in,
                              void* d_out, int out_size, void* d_ws, size_t ws_size,
                              hipStream_t stream) {
    const float* x    = (const float*)d_in[0];
    const float* wqkv = (const float*)d_in[1];
    const float* wo   = (const float*)d_in[2];
    const float* qw   = (const float*)d_in[3];
    const float* kw   = (const float*)d_in[4];
    const float* fc   = (const float*)d_in[5];
    const float* fs   = (const float*)d_in[6];
    float* out = (float*)d_out;
    char* ws = (char*)d_ws;

    u16*   xb    = (u16*)(ws + 0);           // 4096x2048 bf16   (16 MB)
    u16*   wqkvb = (u16*)(ws + 16777216);    // 3072x2048 bf16   (12 MB)
    u16*   wob   = (u16*)(ws + 29360128);    // 2048x2048 bf16   ( 8 MB)
    float* qkv   = (float*)(ws + 37748736);  // 4096x3072 fp32   (48 MB)
    u16*   qb    = (u16*)(ws + 88080384);    // [2,16,2048,128]  (16 MB)
    u16*   kb    = (u16*)(ws + 104857600);   // [2,4,2048,128]   ( 4 MB)
    u16*   vt    = (u16*)(ws + 109051904);   // [2,4,128,2048]   ( 4 MB)
    u16*   ab    = (u16*)(ws + 113246208);   // 4096x2048 bf16   (16 MB)

    cvt_bf16<<<8192, 256, 0, stream>>>(x, xb, 2097152);
    cvt_bf16<<<6144, 256, 0, stream>>>(wqkv, wqkvb, 1572864);
    cvt_bf16<<<4096, 256, 0, stream>>>(wo, wob, 1048576);
    gemm_bt<<<dim3(24, 32), 256, 0, stream>>>(xb, wqkvb, qkv, 4096, 3072, 2048);
    normrope<<<20480, 256, 0, stream>>>(qkv, qw, kw, fc, fs, qb, kb);
    vtrans<<<128, 256, 0, stream>>>(qkv, vt);
    flash_attn<<<dim3(16, 16, 2), 256, 0, stream>>>(qb, kb, vt, ab);
    gemm_bt<<<dim3(16, 32), 256, 0, stream>>>(ab, wob, out, 4096, 2048, 2048);
}

// Round 3
// 361.295 us; speedup vs baseline: 1.3205x; 1.2404x over previous
//
#include <hip/hip_runtime.h>

typedef unsigned short u16;
typedef __bf16 bf16x8 __attribute__((ext_vector_type(8)));
typedef u16 u16x8 __attribute__((ext_vector_type(8)));
typedef float f32x4 __attribute__((ext_vector_type(4)));
typedef float f32x16 __attribute__((ext_vector_type(16)));

__device__ __forceinline__ u16 f2bf(float f) {
    unsigned u = __float_as_uint(f);
    return (u16)((u + 0x7fffu + ((u >> 16) & 1u)) >> 16);
}
__device__ __forceinline__ unsigned pk2(float a, float b) {
    return (unsigned)f2bf(a) | ((unsigned)f2bf(b) << 16);
}

// ---------------- fp32 -> bf16 convert ----------------
__global__ void cvt_bf16(const float* __restrict__ src, u16* __restrict__ dst, int n4) {
    int i = blockIdx.x * 256 + threadIdx.x;
    if (i >= n4) return;
    float4 v = *(const float4*)(src + (size_t)i * 4);
    uint2 o; o.x = pk2(v.x, v.y); o.y = pk2(v.z, v.w);
    *(uint2*)(dst + (size_t)i * 4) = o;
}

// ---------------- bf16 GEMM: C[M][N] = A[M][K] * B[N][K]^T, fp32 out --------
__global__ __launch_bounds__(256)
void gemm_bt(const u16* __restrict__ A, const u16* __restrict__ B,
             float* __restrict__ C, int M, int N, int K) {
    __shared__ u16 As[128 * 32];
    __shared__ u16 Bs[128 * 32];
    const int tid = threadIdx.x;
    const int wave = tid >> 6, lane = tid & 63;
    const int quad = lane >> 4, l16 = lane & 15;
    const size_t bm = (size_t)blockIdx.y * 128;
    const size_t bn = (size_t)blockIdx.x * 128;
    const int wr = (wave >> 1) * 64;
    const int wc = (wave & 1) * 64;

    f32x4 acc[4][4] = {};

    const u16* Ab = A + bm * K;
    const u16* Bb = B + bn * K;
    const int strow = wave * 32 + (lane >> 2);
    const int stk = (lane & 3) * 8;

    for (int k0 = 0; k0 < K; k0 += 32) {
        __syncthreads();
#pragma unroll
        for (int c = 0; c < 2; ++c) {
            const u16* ga = Ab + (size_t)(strow + c * 16) * K + k0 + stk;
            const u16* gb = Bb + (size_t)(strow + c * 16) * K + k0 + stk;
            __builtin_amdgcn_global_load_lds(
                (__attribute__((address_space(1))) void*)ga,
                (__attribute__((address_space(3))) void*)&As[(wave * 32 + c * 16) * 32],
                16, 0, 0);
            __builtin_amdgcn_global_load_lds(
                (__attribute__((address_space(1))) void*)gb,
                (__attribute__((address_space(3))) void*)&Bs[(wave * 32 + c * 16) * 32],
                16, 0, 0);
        }
        __syncthreads();
        bf16x8 af[4], bfr[4];
#pragma unroll
        for (int mt = 0; mt < 4; ++mt)
            af[mt] = *(const bf16x8*)&As[(wr + mt * 16 + l16) * 32 + quad * 8];
#pragma unroll
        for (int nt = 0; nt < 4; ++nt)
            bfr[nt] = *(const bf16x8*)&Bs[(wc + nt * 16 + l16) * 32 + quad * 8];
#pragma unroll
        for (int mt = 0; mt < 4; ++mt)
#pragma unroll
            for (int nt = 0; nt < 4; ++nt)
                acc[mt][nt] = __builtin_amdgcn_mfma_f32_16x16x32_bf16(
                    af[mt], bfr[nt], acc[mt][nt], 0, 0, 0);
    }
#pragma unroll
    for (int mt = 0; mt < 4; ++mt)
#pragma unroll
        for (int nt = 0; nt < 4; ++nt)
#pragma unroll
            for (int r = 0; r < 4; ++r)
                C[(bm + wr + mt * 16 + quad * 4 + r) * (size_t)N + bn + wc + nt * 16 + l16] =
                    acc[mt][nt][r];
}

// ---------------- RMSNorm + RoPE for q,k. Q pre-scaled by scale*log2(e) -----
__global__ __launch_bounds__(256)
void normrope(const float* __restrict__ qkv, const float* __restrict__ qw,
              const float* __restrict__ kw, const float* __restrict__ fcos,
              const float* __restrict__ fsin, u16* __restrict__ qb, u16* __restrict__ kb) {
    int gw = blockIdx.x * 4 + (threadIdx.x >> 6);
    int lane = threadIdx.x & 63;
    int row = gw / 20;
    int task = gw - row * 20;
    int s = row & 2047;
    int b = row >> 11;
    const float* src;
    const float* w;
    u16* dst;
    float scl;
    if (task < 16) {
        src = qkv + (size_t)row * 3072 + task * 128;
        w = qw;
        dst = qb + ((size_t)(b * 16 + task) * 2048 + s) * 128;
        scl = 0.08838834764831845f * 1.4426950408889634f;  // scale * log2(e)
    } else {
        int kh = task - 16;
        src = qkv + (size_t)row * 3072 + 2048 + kh * 128;
        w = kw;
        dst = kb + ((size_t)(b * 4 + kh) * 2048 + s) * 128;
        scl = 1.0f;
    }
    float2 x = *(const float2*)(src + lane * 2);
    float ss = x.x * x.x + x.y * x.y;
#pragma unroll
    for (int off = 32; off >= 1; off >>= 1) ss += __shfl_xor(ss, off);
    float r = rsqrtf(ss * (1.0f / 128.0f) + 1.1920928955078125e-07f) * scl;
    float y0 = x.x * r * w[lane * 2];
    float y1 = x.y * r * w[lane * 2 + 1];
    float c0 = fcos[(size_t)s * 128 + lane * 2], c1 = fcos[(size_t)s * 128 + lane * 2 + 1];
    float s0 = fsin[(size_t)s * 128 + lane * 2], s1 = fsin[(size_t)s * 128 + lane * 2 + 1];
    dst[lane * 2]     = f2bf(y0 * c0 - y1 * s0);
    dst[lane * 2 + 1] = f2bf(y1 * c1 + y0 * s1);
}

// ---------------- V transpose: qkv fp32 -> vt bf16 [b,kv,d,s] ----------------
__global__ __launch_bounds__(256)
void vtrans(const float* __restrict__ qkv, u16* __restrict__ vt) {
    __shared__ u16 tile[128 * 132];
    int blk = blockIdx.x;
    int kblk = blk & 15, kh = (blk >> 4) & 3, b = blk >> 6;
    int tid = threadIdx.x;
    const float* src = qkv + (size_t)(b * 2048 + kblk * 128) * 3072 + 2560 + kh * 128;
#pragma unroll
    for (int it = 0; it < 16; ++it) {
        int flat4 = tid + it * 256;
        int row = flat4 >> 5, c4 = flat4 & 31;
        float4 v = *(const float4*)(src + (size_t)row * 3072 + c4 * 4);
        u16* d = &tile[row * 132 + c4 * 4];
        d[0] = f2bf(v.x); d[1] = f2bf(v.y); d[2] = f2bf(v.z); d[3] = f2bf(v.w);
    }
    __syncthreads();
    int dd = tid >> 1, half = tid & 1;
    u16* dst = vt + ((size_t)(b * 4 + kh) * 128 + dd) * 2048 + kblk * 128 + half * 64;
#pragma unroll
    for (int k8 = 0; k8 < 8; ++k8) {
        u16x8 o;
#pragma unroll
        for (int j = 0; j < 8; ++j) o[j] = tile[(half * 64 + k8 * 8 + j) * 132 + dd];
        *(u16x8*)(dst + k8 * 8) = o;
    }
}

// ---------------- flash attention v3: 32x32 mfma, reg-P, dbuf, swizzled LDS --
// block=(qt,hh,bb): 128 q-rows, 4 waves x 32 q-rows, 64-key tiles.
#define KBUF(c) ((c) * 8192)
#define VBUF(c) (16384 + (c) * 8192)
__global__ __launch_bounds__(256, 2)
void flash_attn(const u16* __restrict__ qb, const u16* __restrict__ kb,
                const u16* __restrict__ vt, u16* __restrict__ ab) {
    __shared__ u16 smem[32768];     // [K0|K1|V0|V1], each 64x128 / 128x64, swizzled
    __shared__ float Llds[128];

    const int tid = threadIdx.x;
    const int wave = tid >> 6, lane = tid & 63;
    const int hf = lane >> 5, c32 = lane & 31;
    const int qt = blockIdx.x, hh = blockIdx.y, bb = blockIdx.z;
    const int kh = hh >> 2;

    const u16* Qbase = qb + (size_t)(bb * 16 + hh) * 2048 * 128;
    const u16* Kbase = kb + (size_t)(bb * 4 + kh) * 2048 * 128;
    const u16* Vbase = vt + (size_t)(bb * 4 + kh) * 128 * 2048;

    // resident Q fragments (B-operand): n = c32 (qrow), k = hf*8 + j
    bf16x8 aq[8];
#pragma unroll
    for (int kq = 0; kq < 8; ++kq)
        aq[kq] = *(const bf16x8*)(Qbase +
            (size_t)(qt * 128 + wave * 32 + c32) * 128 + kq * 16 + hf * 8);

    f32x16 O[4] = {};
    float lacc = 0.f;

    // staging index helpers
    const int st_key = tid >> 4, st_c16 = tid & 15;   // K: 16 keys per 256-thread pass
    const int st_d = tid >> 3, st_c8 = tid & 7;       // V: 32 d-rows per pass

    u16x8 kreg[4], vreg[4];
    // ---- prologue: load + stage tile 0 into buffer 0 ----
#pragma unroll
    for (int it = 0; it < 4; ++it) {
        int key = st_key + it * 16, d = st_d + it * 32;
        kreg[it] = *(const u16x8*)(Kbase + (size_t)key * 128 + st_c16 * 8);
        vreg[it] = *(const u16x8*)(Vbase + (size_t)d * 2048 + st_c8 * 8);
    }
#pragma unroll
    for (int it = 0; it < 4; ++it) {
        int key = st_key + it * 16, d = st_d + it * 32;
        *(u16x8*)&smem[KBUF(0) + key * 128 + ((st_c16 ^ (key & 7)) * 8)] = kreg[it];
        *(u16x8*)&smem[VBUF(0) + d * 64 + ((st_c8 ^ (d & 7)) * 8)] = vreg[it];
    }
    __syncthreads();

    for (int kt = 0; kt < 32; ++kt) {
        const int cur = kt & 1, nxt = cur ^ 1;
        // issue next tile's global loads (latency covered by QK below)
        if (kt < 31) {
            const int key0n = (kt + 1) * 64;
#pragma unroll
            for (int it = 0; it < 4; ++it) {
                int key = st_key + it * 16, d = st_d + it * 32;
                kreg[it] = *(const u16x8*)(Kbase + (size_t)(key0n + key) * 128 + st_c16 * 8);
                vreg[it] = *(const u16x8*)(Vbase + (size_t)d * 2048 + key0n + st_c8 * 8);
            }
        }

        // S^T = K * Q^T via 32x32x16: C row = key, col = qrow
        f32x16 sc[2] = {};
#pragma unroll
        for (int kq = 0; kq < 8; ++kq) {
#pragma unroll
            for (int mt = 0; mt < 2; ++mt) {
                bf16x8 kf = *(const bf16x8*)&smem[KBUF(cur) + (mt * 32 + c32) * 128 +
                                                 (((kq * 2 + hf) ^ (c32 & 7)) * 8)];
                sc[mt] = __builtin_amdgcn_mfma_f32_32x32x16_bf16(kf, aq[kq], sc[mt], 0, 0, 0);
            }
        }

        // p = exp2(s); accumulate l; pack to dwords (2 keys each)
        int pdw[2][8];
#pragma unroll
        for (int mt = 0; mt < 2; ++mt) {
            float p[16];
#pragma unroll
            for (int r = 0; r < 16; ++r) {
                p[r] = __builtin_amdgcn_exp2f(sc[mt][r]);
                lacc += p[r];
            }
#pragma unroll
            for (int i = 0; i < 8; ++i) pdw[mt][i] = (int)pk2(p[2 * i], p[2 * i + 1]);
        }

        // stage next tile into other buffer (waits vmcnt automatically)
        if (kt < 31) {
#pragma unroll
            for (int it = 0; it < 4; ++it) {
                int key = st_key + it * 16, d = st_d + it * 32;
                *(u16x8*)&smem[KBUF(nxt) + key * 128 + ((st_c16 ^ (key & 7)) * 8)] = kreg[it];
                *(u16x8*)&smem[VBUF(nxt) + d * 64 + ((st_c8 ^ (d & 7)) * 8)] = vreg[it];
            }
        }

        // build P A-frags via xor-32 lane exchange, then O += P V
#pragma unroll
        for (int kc = 0; kc < 4; ++kc) {
            const int mt = kc >> 1, L = kc & 1;
            int s0 = hf ? pdw[mt][4 * L + 0] : pdw[mt][4 * L + 2];
            int s1 = hf ? pdw[mt][4 * L + 1] : pdw[mt][4 * L + 3];
            int r0 = __shfl_xor(s0, 32);
            int r1 = __shfl_xor(s1, 32);
            union { int i[4]; bf16x8 v; } u;
            u.i[0] = hf ? r0 : pdw[mt][4 * L + 0];
            u.i[1] = hf ? r1 : pdw[mt][4 * L + 1];
            u.i[2] = hf ? pdw[mt][4 * L + 2] : r0;
            u.i[3] = hf ? pdw[mt][4 * L + 3] : r1;
#pragma unroll
            for (int dt = 0; dt < 4; ++dt) {
                bf16x8 vf = *(const bf16x8*)&smem[VBUF(cur) + (dt * 32 + c32) * 64 +
                                                 (((kc * 2 + hf) ^ (c32 & 7)) * 8)];
                O[dt] = __builtin_amdgcn_mfma_f32_32x32x16_bf16(u.v, vf, O[dt], 0, 0, 0);
            }
        }
        __syncthreads();
    }

    // softmax denominator per q-row (one xor-32 + broadcast table)
    float l = lacc + __shfl_xor(lacc, 32);
    if (hf == 0) Llds[wave * 32 + c32] = l;   // qrow = c32

    // O: col(c32) = d-in-tile, rows(regs) = qrow = (r&3)+8*(r>>2)+4*hf
    float inv[16];
#pragma unroll
    for (int r = 0; r < 16; ++r)
        inv[r] = __builtin_amdgcn_rcpf(Llds[wave * 32 + (r & 3) + 8 * (r >> 2) + 4 * hf]);

    // transpose O through LDS scratch (reuses K/V space; loop's final barrier
    // guarantees all tile reads are done) then coalesced global stores
    u16* scr = &smem[wave * 32 * 136];   // [qrow][136 d]
#pragma unroll
    for (int dt = 0; dt < 4; ++dt)
#pragma unroll
        for (int r = 0; r < 16; ++r) {
            int q_r = (r & 3) + 8 * (r >> 2) + 4 * hf;
            scr[q_r * 136 + dt * 32 + c32] = f2bf(O[dt][r] * inv[r]);
        }
#pragma unroll
    for (int it = 0; it < 8; ++it) {
        int f = it * 64 + lane;
        int row = f >> 4, c = f & 15;
        u16x8 v = *(const u16x8*)&scr[row * 136 + c * 8];
        int qg = qt * 128 + wave * 32 + row;
        *(u16x8*)(ab + ((size_t)(bb * 2048 + qg)) * 2048 + hh * 128 + c * 8) = v;
    }
}

// ---------------- host launch ----------------
extern "C" void kernel_launch(void* const* d_in, const int* in_sizes, int n_in,
                              void* d_out, int out_size, void* d_ws, size_t ws_size,
                              hipStream_t stream) {
    const float* x    = (const float*)d_in[0];
    const float* wqkv = (const float*)d_in[1];
    const float* wo   = (const float*)d_in[2];
    const float* qw   = (const float*)d_in[3];
    const float* kw   = (const float*)d_in[4];
    const float* fc   = (const float*)d_in[5];
    const float* fs   = (const float*)d_in[6];
    float* out = (float*)d_out;
    char* ws = (char*)d_ws;

    u16*   xb    = (u16*)(ws + 0);           // 4096x2048 bf16   (16 MB)
    u16*   wqkvb = (u16*)(ws + 16777216);    // 3072x2048 bf16   (12 MB)
    u16*   wob   = (u16*)(ws + 29360128);    // 2048x2048 bf16   ( 8 MB)
    float* qkv   = (float*)(ws + 37748736);  // 4096x3072 fp32   (48 MB)
    u16*   qb    = (u16*)(ws + 88080384);    // [2,16,2048,128]  (16 MB)
    u16*   kb    = (u16*)(ws + 104857600);   // [2,4,2048,128]   ( 4 MB)
    u16*   vt    = (u16*)(ws + 109051904);   // [2,4,128,2048]   ( 4 MB)
    u16*   ab    = (u16*)(ws + 113246208);   // 4096x2048 bf16   (16 MB)

    cvt_bf16<<<8192, 256, 0, stream>>>(x, xb, 2097152);
    cvt_bf16<<<6144, 256, 0, stream>>>(wqkv, wqkvb, 1572864);
    cvt_bf16<<<4096, 256, 0, stream>>>(wo, wob, 1048576);
    gemm_bt<<<dim3(24, 32), 256, 0, stream>>>(xb, wqkvb, qkv, 4096, 3072, 2048);
    normrope<<<20480, 256, 0, stream>>>(qkv, qw, kw, fc, fs, qb, kb);
    vtrans<<<128, 256, 0, stream>>>(qkv, vt);
    flash_attn<<<dim3(16, 16, 2), 256, 0, stream>>>(qb, kb, vt, ab);
    gemm_bt<<<dim3(16, 32), 256, 0, stream>>>(ab, wob, out, 4096, 2048, 2048);
}

// Round 4
// 333.329 us; speedup vs baseline: 1.4313x; 1.0839x over previous
//
#include <hip/hip_runtime.h>
#include <hip/hip_bf16.h>

typedef unsigned short u16;
typedef __bf16 bf16x8 __attribute__((ext_vector_type(8)));
typedef __bf16 bf16x4 __attribute__((ext_vector_type(4)));
typedef u16 u16x8 __attribute__((ext_vector_type(8)));
typedef float f32x4 __attribute__((ext_vector_type(4)));
typedef float f32x16 __attribute__((ext_vector_type(16)));

__device__ __forceinline__ u16 f2bf(float f) {
    unsigned u = __float_as_uint(f);
    return (u16)((u + 0x7fffu + ((u >> 16) & 1u)) >> 16);
}
__device__ __forceinline__ unsigned pkbf2(float a, float b) {
    __hip_bfloat162 h = __float22bfloat162_rn(make_float2(a, b));
    return *(unsigned*)&h;
}

// ---------------- fp32 -> bf16 convert ----------------
__global__ void cvt_bf16(const float* __restrict__ src, u16* __restrict__ dst, int n4) {
    int i = blockIdx.x * 256 + threadIdx.x;
    if (i >= n4) return;
    float4 v = *(const float4*)(src + (size_t)i * 4);
    uint2 o; o.x = pkbf2(v.x, v.y); o.y = pkbf2(v.z, v.w);
    *(uint2*)(dst + (size_t)i * 4) = o;
}

// ---------------- GEMM core: 128x128 tile, BK=32, reg-staged dbuf LDS, ------
// single barrier per K-iter. A row-block and B row-block pre-offset by caller.
__device__ __forceinline__ void gemm_core(const u16* __restrict__ Ab,
                                          const u16* __restrict__ Bb, int K,
                                          f32x4 acc[4][4], int wave, int lane) {
    __shared__ u16 As[2][128 * 32];
    __shared__ u16 Bs[2][128 * 32];
    const int quad = lane >> 4, l16 = lane & 15;
    const int wr = (wave >> 1) * 64, wc = (wave & 1) * 64;
    const int strow = lane >> 2;          // 0..15 within wave's 32-row slab
    const int stk = (lane & 3) * 8;       // k-offset elems

    const u16* pa0 = Ab + (size_t)(wave * 32 + strow) * K + stk;
    const u16* pa1 = pa0 + (size_t)16 * K;
    const u16* pb0 = Bb + (size_t)(wave * 32 + strow) * K + stk;
    const u16* pb1 = pb0 + (size_t)16 * K;
    const int lrow0 = (wave * 32 + strow) * 32 + stk;
    const int lrow1 = (wave * 32 + 16 + strow) * 32 + stk;

    // prologue: tile 0
    u16x8 a0 = *(const u16x8*)pa0, a1 = *(const u16x8*)pa1;
    u16x8 b0 = *(const u16x8*)pb0, b1 = *(const u16x8*)pb1;
    *(u16x8*)&As[0][lrow0] = a0; *(u16x8*)&As[0][lrow1] = a1;
    *(u16x8*)&Bs[0][lrow0] = b0; *(u16x8*)&Bs[0][lrow1] = b1;
    __syncthreads();

    const int nk = K >> 5;
    for (int kt = 0; kt < nk; ++kt) {
        const int cur = kt & 1, nxt = cur ^ 1;
        if (kt + 1 < nk) {
            const int off = (kt + 1) * 32;
            a0 = *(const u16x8*)(pa0 + off); a1 = *(const u16x8*)(pa1 + off);
            b0 = *(const u16x8*)(pb0 + off); b1 = *(const u16x8*)(pb1 + off);
        }
        bf16x8 af[4], bfr[4];
#pragma unroll
        for (int mt = 0; mt < 4; ++mt)
            af[mt] = *(const bf16x8*)&As[cur][(wr + mt * 16 + l16) * 32 + quad * 8];
#pragma unroll
        for (int nt = 0; nt < 4; ++nt)
            bfr[nt] = *(const bf16x8*)&Bs[cur][(wc + nt * 16 + l16) * 32 + quad * 8];
#pragma unroll
        for (int mt = 0; mt < 4; ++mt)
#pragma unroll
            for (int nt = 0; nt < 4; ++nt)
                acc[mt][nt] = __builtin_amdgcn_mfma_f32_16x16x32_bf16(
                    af[mt], bfr[nt], acc[mt][nt], 0, 0, 0);
        if (kt + 1 < nk) {
            *(u16x8*)&As[nxt][lrow0] = a0; *(u16x8*)&As[nxt][lrow1] = a1;
            *(u16x8*)&Bs[nxt][lrow0] = b0; *(u16x8*)&Bs[nxt][lrow1] = b1;
        }
        __syncthreads();
    }
}

// ---------------- plain GEMM (o-proj): C = A * B^T, fp32 out ----------------
__global__ __launch_bounds__(256)
void gemm_bt(const u16* __restrict__ A, const u16* __restrict__ B,
             float* __restrict__ C, int M, int N, int K) {
    const int tid = threadIdx.x, wave = tid >> 6, lane = tid & 63;
    const int quad = lane >> 4, l16 = lane & 15;
    const int wr = (wave >> 1) * 64, wc = (wave & 1) * 64;
    const size_t bm = (size_t)blockIdx.y * 128, bn = (size_t)blockIdx.x * 128;
    f32x4 acc[4][4] = {};
    gemm_core(A + bm * K, B + bn * K, K, acc, wave, lane);
#pragma unroll
    for (int mt = 0; mt < 4; ++mt)
#pragma unroll
        for (int nt = 0; nt < 4; ++nt)
#pragma unroll
            for (int r = 0; r < 4; ++r)
                C[(bm + wr + mt * 16 + quad * 4 + r) * (size_t)N + bn + wc + nt * 16 + l16] =
                    acc[mt][nt][r];
}

// ---------------- fused QKV GEMM: RMSNorm+RoPE (q,k) / transpose (v) --------
// N-tile tn: 0..15 = q head, 16..19 = k head, 20..23 = v head. 128 cols = head dim.
__global__ __launch_bounds__(256)
void gemm_qkv(const u16* __restrict__ xb, const u16* __restrict__ wq,
              const float* __restrict__ qw, const float* __restrict__ kw,
              const float* __restrict__ fcos, const float* __restrict__ fsin,
              u16* __restrict__ qb, u16* __restrict__ kb, u16* __restrict__ vt) {
    const int tid = threadIdx.x, wave = tid >> 6, lane = tid & 63;
    const int quad = lane >> 4, l16 = lane & 15;
    const int wr = (wave >> 1) * 64, wc = (wave & 1) * 64;
    const int tn = blockIdx.x, bmb = blockIdx.y;
    f32x4 acc[4][4] = {};
    gemm_core(xb + (size_t)bmb * 128 * 2048, wq + (size_t)tn * 128 * 2048, 2048,
              acc, wave, lane);

    const int b = bmb >> 4;
    const int sbase = (bmb & 15) * 128 + wr;   // + mt*16 + quad*4 + r

    if (tn >= 20) {
        // V: bf16 + transpose store, 4 consecutive s per bf16x4
        const int kv = tn - 20;
        u16* base = vt + (size_t)(b * 4 + kv) * 128 * 2048;
#pragma unroll
        for (int mt = 0; mt < 4; ++mt) {
            int s0 = sbase + mt * 16 + quad * 4;
#pragma unroll
            for (int nt = 0; nt < 4; ++nt) {
                int col = wc + nt * 16 + l16;
                bf16x4 pv;
#pragma unroll
                for (int r = 0; r < 4; ++r) pv[r] = (__bf16)acc[mt][nt][r];
                *(bf16x4*)(base + (size_t)col * 2048 + s0) = pv;
            }
        }
        return;
    }

    // Q/K: RMSNorm + RoPE
    __shared__ float red[2][128];
    float ssq[4][4];
#pragma unroll
    for (int mt = 0; mt < 4; ++mt)
#pragma unroll
        for (int r = 0; r < 4; ++r) {
            float t = 0.f;
#pragma unroll
            for (int nt = 0; nt < 4; ++nt) t += acc[mt][nt][r] * acc[mt][nt][r];
#pragma unroll
            for (int off = 1; off <= 8; off <<= 1) t += __shfl_xor(t, off);
            ssq[mt][r] = t;
        }
    if (l16 == 0)
#pragma unroll
        for (int mt = 0; mt < 4; ++mt)
#pragma unroll
            for (int r = 0; r < 4; ++r)
                red[wave & 1][wr + mt * 16 + quad * 4 + r] = ssq[mt][r];
    __syncthreads();

    const float qscl = (tn < 16) ? 0.08838834764831845f * 1.4426950408889634f : 1.0f;
    const float* wp = (tn < 16) ? qw : kw;
    float wcol[4];
#pragma unroll
    for (int nt = 0; nt < 4; ++nt) wcol[nt] = wp[wc + nt * 16 + l16];
    u16* dstbase = (tn < 16) ? qb + (size_t)(b * 16 + tn) * 2048 * 128
                             : kb + (size_t)(b * 4 + (tn - 16)) * 2048 * 128;
    const float sgn = (l16 & 1) ? 1.f : -1.f;

#pragma unroll
    for (int mt = 0; mt < 4; ++mt) {
#pragma unroll
        for (int r = 0; r < 4; ++r) {
            int row = wr + mt * 16 + quad * 4 + r;
            float var = (red[0][row] + red[1][row]) * (1.0f / 128.0f);
            float rms = rsqrtf(var + 1.1920928955078125e-07f) * qscl;
            int s = sbase + mt * 16 + quad * 4 + r;
            const float* fc = fcos + (size_t)s * 128 + wc;
            const float* fn = fsin + (size_t)s * 128 + wc;
            u16* drow = dstbase + (size_t)s * 128 + wc;
#pragma unroll
            for (int nt = 0; nt < 4; ++nt) {
                float y = acc[mt][nt][r] * rms * wcol[nt];
                float yp = __shfl_xor(y, 1);
                float o = y * fc[nt * 16 + l16] + sgn * yp * fn[nt * 16 + l16];
                drow[nt * 16 + l16] = f2bf(o);
            }
        }
    }
}

// ---------------- flash attention v3: 32x32 mfma, reg-P, dbuf, swizzled LDS --
#define KBUF(c) ((c) * 8192)
#define VBUF(c) (16384 + (c) * 8192)
__global__ __launch_bounds__(256, 2)
void flash_attn(const u16* __restrict__ qb, const u16* __restrict__ kb,
                const u16* __restrict__ vt, u16* __restrict__ ab) {
    __shared__ u16 smem[32768];
    __shared__ float Llds[128];

    const int tid = threadIdx.x;
    const int wave = tid >> 6, lane = tid & 63;
    const int hf = lane >> 5, c32 = lane & 31;
    const int qt = blockIdx.x, hh = blockIdx.y, bb = blockIdx.z;
    const int kh = hh >> 2;

    const u16* Qbase = qb + (size_t)(bb * 16 + hh) * 2048 * 128;
    const u16* Kbase = kb + (size_t)(bb * 4 + kh) * 2048 * 128;
    const u16* Vbase = vt + (size_t)(bb * 4 + kh) * 128 * 2048;

    bf16x8 aq[8];
#pragma unroll
    for (int kq = 0; kq < 8; ++kq)
        aq[kq] = *(const bf16x8*)(Qbase +
            (size_t)(qt * 128 + wave * 32 + c32) * 128 + kq * 16 + hf * 8);

    f32x16 O[4] = {};
    float lacc = 0.f;

    const int st_key = tid >> 4, st_c16 = tid & 15;
    const int st_d = tid >> 3, st_c8 = tid & 7;

    u16x8 kreg[4], vreg[4];
#pragma unroll
    for (int it = 0; it < 4; ++it) {
        int key = st_key + it * 16, d = st_d + it * 32;
        kreg[it] = *(const u16x8*)(Kbase + (size_t)key * 128 + st_c16 * 8);
        vreg[it] = *(const u16x8*)(Vbase + (size_t)d * 2048 + st_c8 * 8);
    }
#pragma unroll
    for (int it = 0; it < 4; ++it) {
        int key = st_key + it * 16, d = st_d + it * 32;
        *(u16x8*)&smem[KBUF(0) + key * 128 + ((st_c16 ^ (key & 7)) * 8)] = kreg[it];
        *(u16x8*)&smem[VBUF(0) + d * 64 + ((st_c8 ^ (d & 7)) * 8)] = vreg[it];
    }
    __syncthreads();

    for (int kt = 0; kt < 32; ++kt) {
        const int cur = kt & 1, nxt = cur ^ 1;
        if (kt < 31) {
            const int key0n = (kt + 1) * 64;
#pragma unroll
            for (int it = 0; it < 4; ++it) {
                int key = st_key + it * 16, d = st_d + it * 32;
                kreg[it] = *(const u16x8*)(Kbase + (size_t)(key0n + key) * 128 + st_c16 * 8);
                vreg[it] = *(const u16x8*)(Vbase + (size_t)d * 2048 + key0n + st_c8 * 8);
            }
        }

        f32x16 sc[2] = {};
#pragma unroll
        for (int kq = 0; kq < 8; ++kq) {
#pragma unroll
            for (int mt = 0; mt < 2; ++mt) {
                bf16x8 kf = *(const bf16x8*)&smem[KBUF(cur) + (mt * 32 + c32) * 128 +
                                                 (((kq * 2 + hf) ^ (c32 & 7)) * 8)];
                sc[mt] = __builtin_amdgcn_mfma_f32_32x32x16_bf16(kf, aq[kq], sc[mt], 0, 0, 0);
            }
        }

        int pdw[2][8];
#pragma unroll
        for (int mt = 0; mt < 2; ++mt) {
            float p[16];
#pragma unroll
            for (int r = 0; r < 16; ++r) {
                p[r] = __builtin_amdgcn_exp2f(sc[mt][r]);
                lacc += p[r];
            }
#pragma unroll
            for (int i = 0; i < 8; ++i) pdw[mt][i] = (int)pkbf2(p[2 * i], p[2 * i + 1]);
        }

        if (kt < 31) {
#pragma unroll
            for (int it = 0; it < 4; ++it) {
                int key = st_key + it * 16, d = st_d + it * 32;
                *(u16x8*)&smem[KBUF(nxt) + key * 128 + ((st_c16 ^ (key & 7)) * 8)] = kreg[it];
                *(u16x8*)&smem[VBUF(nxt) + d * 64 + ((st_c8 ^ (d & 7)) * 8)] = vreg[it];
            }
        }

#pragma unroll
        for (int kc = 0; kc < 4; ++kc) {
            const int mt = kc >> 1, L = kc & 1;
            int s0 = hf ? pdw[mt][4 * L + 0] : pdw[mt][4 * L + 2];
            int s1 = hf ? pdw[mt][4 * L + 1] : pdw[mt][4 * L + 3];
            int r0 = __shfl_xor(s0, 32);
            int r1 = __shfl_xor(s1, 32);
            union { int i[4]; bf16x8 v; } u;
            u.i[0] = hf ? r0 : pdw[mt][4 * L + 0];
            u.i[1] = hf ? r1 : pdw[mt][4 * L + 1];
            u.i[2] = hf ? pdw[mt][4 * L + 2] : r0;
            u.i[3] = hf ? pdw[mt][4 * L + 3] : r1;
#pragma unroll
            for (int dt = 0; dt < 4; ++dt) {
                bf16x8 vf = *(const bf16x8*)&smem[VBUF(cur) + (dt * 32 + c32) * 64 +
                                                 (((kc * 2 + hf) ^ (c32 & 7)) * 8)];
                O[dt] = __builtin_amdgcn_mfma_f32_32x32x16_bf16(u.v, vf, O[dt], 0, 0, 0);
            }
        }
        __syncthreads();
    }

    float l = lacc + __shfl_xor(lacc, 32);
    if (hf == 0) Llds[wave * 32 + c32] = l;

    float inv[16];
#pragma unroll
    for (int r = 0; r < 16; ++r)
        inv[r] = __builtin_amdgcn_rcpf(Llds[wave * 32 + (r & 3) + 8 * (r >> 2) + 4 * hf]);

    u16* scr = &smem[wave * 32 * 136];
#pragma unroll
    for (int dt = 0; dt < 4; ++dt)
#pragma unroll
        for (int r = 0; r < 16; ++r) {
            int q_r = (r & 3) + 8 * (r >> 2) + 4 * hf;
            scr[q_r * 136 + dt * 32 + c32] = f2bf(O[dt][r] * inv[r]);
        }
#pragma unroll
    for (int it = 0; it < 8; ++it) {
        int f = it * 64 + lane;
        int row = f >> 4, c = f & 15;
        u16x8 v = *(const u16x8*)&scr[row * 136 + c * 8];
        int qg = qt * 128 + wave * 32 + row;
        *(u16x8*)(ab + ((size_t)(bb * 2048 + qg)) * 2048 + hh * 128 + c * 8) = v;
    }
}

// ---------------- host launch ----------------
extern "C" void kernel_launch(void* const* d_in, const int* in_sizes, int n_in,
                              void* d_out, int out_size, void* d_ws, size_t ws_size,
                              hipStream_t stream) {
    const float* x    = (const float*)d_in[0];
    const float* wqkv = (const float*)d_in[1];
    const float* wo   = (const float*)d_in[2];
    const float* qw   = (const float*)d_in[3];
    const float* kw   = (const float*)d_in[4];
    const float* fc   = (const float*)d_in[5];
    const float* fs   = (const float*)d_in[6];
    float* out = (float*)d_out;
    char* ws = (char*)d_ws;

    u16* xb    = (u16*)(ws + 0);          // 4096x2048 bf16 (16 MB)
    u16* wqkvb = (u16*)(ws + 16777216);   // 3072x2048 bf16 (12 MB)
    u16* wob   = (u16*)(ws + 29360128);   // 2048x2048 bf16 ( 8 MB)
    u16* qb    = (u16*)(ws + 37748736);   // [2,16,2048,128] (16 MB)
    u16* kb    = (u16*)(ws + 54525952);   // [2,4,2048,128]  ( 4 MB)
    u16* vt    = (u16*)(ws + 58720256);   // [2,4,128,2048]  ( 4 MB)
    u16* ab    = (u16*)(ws + 62914560);   // 4096x2048 bf16  (16 MB)

    cvt_bf16<<<8192, 256, 0, stream>>>(x, xb, 2097152);
    cvt_bf16<<<6144, 256, 0, stream>>>(wqkv, wqkvb, 1572864);
    cvt_bf16<<<4096, 256, 0, stream>>>(wo, wob, 1048576);
    gemm_qkv<<<dim3(24, 32), 256, 0, stream>>>(xb, wqkvb, qw, kw, fc, fs, qb, kb, vt);
    flash_attn<<<dim3(16, 16, 2), 256, 0, stream>>>(qb, kb, vt, ab);
    gemm_bt<<<dim3(16, 32), 256, 0, stream>>>(ab, wob, out, 4096, 2048, 2048);
}